// Round 1
// baseline (1082.226 us; speedup 1.0000x reference)
//
#include <hip/hip_runtime.h>

#define N_NODES 50000
#define N_EDGES 600000
#define D_IN 128
#define D_OUT 256
#define BM 64
#define BN 64

// Stage 1: weighted scatter-add of h rows into x[dst], 32 lanes per edge.
__global__ __launch_bounds__(256)
void scatter_edges(const float* __restrict__ h,
                   const int* __restrict__ esrc,
                   const int* __restrict__ edst,
                   const float* __restrict__ ew,
                   float* __restrict__ x) {
    int t = blockIdx.x * 256 + threadIdx.x;
    int edge = t >> 5;
    if (edge >= N_EDGES) return;
    int lane4 = (t & 31) * 4;
    int src = esrc[edge];
    int dst = edst[edge];
    float w = ew[edge];
    float4 hv = *reinterpret_cast<const float4*>(h + (size_t)src * D_IN + lane4);
    float* xp = x + (size_t)dst * D_IN + lane4;
    atomicAdd(xp + 0, w * hv.x);
    atomicAdd(xp + 1, w * hv.y);
    atomicAdd(xp + 2, w * hv.z);
    atomicAdd(xp + 3, w * hv.w);
}

// Stage 2: out = relu(x @ W), fp32 tiled GEMM. BM=BN=64, K=128 fully staged.
__global__ __launch_bounds__(256)
void gemm_relu(const float* __restrict__ x,
               const float* __restrict__ W,
               float* __restrict__ out) {
    __shared__ float As[D_IN][BM];   // [k][m], 32 KB
    __shared__ float Bs[D_IN][BN];   // [k][n], 32 KB
    const int t = threadIdx.x;
    const int row0 = blockIdx.x * BM;
    const int col0 = blockIdx.y * BN;

    // Stage A: x[row][k] -> As[k][m] (transpose). LDS writes conflict-free
    // (lanes m=0..63 consecutive words per write).
    {
        const int m = t & 63;
        const int k0 = (t >> 6) * 4;   // 0,4,8,12 per quarter-block
        const int row = row0 + m;
        #pragma unroll
        for (int i = 0; i < 8; ++i) {
            const int k = k0 + i * 16;
            float4 v = make_float4(0.f, 0.f, 0.f, 0.f);
            if (row < N_NODES)
                v = *reinterpret_cast<const float4*>(x + (size_t)row * D_IN + k);
            As[k + 0][m] = v.x;
            As[k + 1][m] = v.y;
            As[k + 2][m] = v.z;
            As[k + 3][m] = v.w;
        }
    }
    // Stage B: W[k][col0+n] -> Bs[k][n]. Contiguous global reads per wave,
    // conflict-free LDS writes.
    {
        const int n = t & 63;
        const int kbase = t >> 6;      // 0..3
        #pragma unroll
        for (int i = 0; i < 32; ++i) {
            const int k = kbase + i * 4;
            Bs[k][n] = W[(size_t)k * D_OUT + col0 + n];
        }
    }
    __syncthreads();

    const int tx = t & 15;            // n-dim, 16 threads
    const int ty = t >> 4;            // m-dim, 16 threads
    float acc[4][4];
    #pragma unroll
    for (int i = 0; i < 4; ++i)
        #pragma unroll
        for (int j = 0; j < 4; ++j) acc[i][j] = 0.f;

    #pragma unroll 8
    for (int k = 0; k < D_IN; ++k) {
        float4 a = *reinterpret_cast<const float4*>(&As[k][ty * 4]);  // b128, bank-clean
        float4 b = *reinterpret_cast<const float4*>(&Bs[k][tx * 4]);  // b128, 2-way (free)
        float av[4] = {a.x, a.y, a.z, a.w};
        float bv[4] = {b.x, b.y, b.z, b.w};
        #pragma unroll
        for (int i = 0; i < 4; ++i)
            #pragma unroll
            for (int j = 0; j < 4; ++j)
                acc[i][j] += av[i] * bv[j];
    }

    #pragma unroll
    for (int i = 0; i < 4; ++i) {
        const int row = row0 + ty * 4 + i;
        if (row >= N_NODES) continue;
        float4 o;
        o.x = fmaxf(acc[i][0], 0.f);
        o.y = fmaxf(acc[i][1], 0.f);
        o.z = fmaxf(acc[i][2], 0.f);
        o.w = fmaxf(acc[i][3], 0.f);
        *reinterpret_cast<float4*>(out + (size_t)row * D_OUT + col0 + tx * 4) = o;
    }
}

extern "C" void kernel_launch(void* const* d_in, const int* in_sizes, int n_in,
                              void* d_out, int out_size, void* d_ws, size_t ws_size,
                              hipStream_t stream) {
    const float* h  = (const float*)d_in[0];
    const int* esrc = (const int*)d_in[1];
    const int* edst = (const int*)d_in[2];
    const float* ew = (const float*)d_in[3];
    const float* Wn = (const float*)d_in[4];
    float* out = (float*)d_out;
    float* x = (float*)d_ws;   // [N_NODES][D_IN] fp32 = 25.6 MB scratch

    hipMemsetAsync(x, 0, (size_t)N_NODES * D_IN * sizeof(float), stream);

    {
        const long long threads_total = (long long)N_EDGES * 32;
        const int blocks = (int)((threads_total + 255) / 256);
        scatter_edges<<<blocks, 256, 0, stream>>>(h, esrc, edst, ew, x);
    }
    {
        dim3 grid((N_NODES + BM - 1) / BM, D_OUT / BN);
        gemm_relu<<<grid, 256, 0, stream>>>(x, Wn, out);
    }
}

// Round 2
// 242.071 us; speedup vs baseline: 4.4707x; 4.4707x over previous
//
#include <hip/hip_runtime.h>

#define N_NODES 50000
#define N_EDGES 600000
#define D_IN 128
#define D_OUT 256
#define BM 64
#define BN 64

// ---------- Stage 1a: histogram of edge destinations ----------
__global__ __launch_bounds__(256)
void hist_dst(const int* __restrict__ edst, int* __restrict__ counts) {
    int e = blockIdx.x * 256 + threadIdx.x;
    if (e < N_EDGES) atomicAdd(&counts[edst[e]], 1);
}

// ---------- Stage 1b: exclusive prefix scan (single block, 1024 thr) ----------
__global__ __launch_bounds__(1024)
void scan_counts(const int* __restrict__ counts, int* __restrict__ row_ptr,
                 int* __restrict__ cursor) {
    __shared__ int wave_sums[16];
    __shared__ int wave_offs[16];
    __shared__ int s_total;
    const int t = threadIdx.x;
    const int lane = t & 63;
    const int wv = t >> 6;
    int running = 0;
    for (int base = 0; base < N_NODES; base += 1024) {
        const int idx = base + t;
        int v = (idx < N_NODES) ? counts[idx] : 0;
        // inclusive wave scan
        int s = v;
        #pragma unroll
        for (int d = 1; d < 64; d <<= 1) {
            int u = __shfl_up(s, d, 64);
            if (lane >= d) s += u;
        }
        if (lane == 63) wave_sums[wv] = s;
        __syncthreads();                       // (A)
        if (wv == 0 && lane < 16) {
            int ws = wave_sums[lane];
            int inc = ws;
            #pragma unroll
            for (int d = 1; d < 16; d <<= 1) {
                int u = __shfl_up(inc, d, 64);
                if (lane >= d) inc += u;
            }
            wave_offs[lane] = inc - ws;        // exclusive within chunk
            if (lane == 15) s_total = inc;     // chunk total
        }
        __syncthreads();                       // (B)
        if (idx < N_NODES) {
            int excl = running + wave_offs[wv] + (s - v);
            row_ptr[idx] = excl;
            cursor[idx] = excl;
        }
        running += s_total;
    }
    if (t == 0) row_ptr[N_NODES] = running;
}

// ---------- Stage 1c: scatter edges into CSR slots ----------
__global__ __launch_bounds__(256)
void fill_csr(const int* __restrict__ esrc, const int* __restrict__ edst,
              const float* __restrict__ ew, int* __restrict__ cursor,
              int* __restrict__ srt_src, float* __restrict__ srt_w) {
    int e = blockIdx.x * 256 + threadIdx.x;
    if (e >= N_EDGES) return;
    int d = edst[e];
    int p = atomicAdd(&cursor[d], 1);
    srt_src[p] = esrc[e];
    srt_w[p] = ew[e];
}

// ---------- Stage 1d: gather-reduce, one wave per node ----------
__global__ __launch_bounds__(256)
void gather_nodes(const float* __restrict__ h,
                  const int* __restrict__ row_ptr,
                  const int* __restrict__ srt_src,
                  const float* __restrict__ srt_w,
                  float* __restrict__ x) {
    const int wv = threadIdx.x >> 6;
    const int lane = threadIdx.x & 63;
    const int n = blockIdx.x * 4 + wv;
    if (n >= N_NODES) return;
    const int beg = row_ptr[n];
    const int end = row_ptr[n + 1];
    float2 acc = make_float2(0.f, 0.f);
    for (int e = beg; e < end; ++e) {
        const int s = srt_src[e];     // wave-uniform load
        const float w = srt_w[e];
        float2 v = *reinterpret_cast<const float2*>(h + (size_t)s * D_IN + lane * 2);
        acc.x += w * v.x;
        acc.y += w * v.y;
    }
    *reinterpret_cast<float2*>(x + (size_t)n * D_IN + lane * 2) = acc;
}

// ---------- Stage 2: out = relu(x @ W), fp32 tiled GEMM ----------
__global__ __launch_bounds__(256)
void gemm_relu(const float* __restrict__ x,
               const float* __restrict__ W,
               float* __restrict__ out) {
    __shared__ float As[D_IN][BM];
    __shared__ float Bs[D_IN][BN];
    const int t = threadIdx.x;
    const int row0 = blockIdx.x * BM;
    const int col0 = blockIdx.y * BN;

    {
        const int m = t & 63;
        const int k0 = (t >> 6) * 4;
        const int row = row0 + m;
        #pragma unroll
        for (int i = 0; i < 8; ++i) {
            const int k = k0 + i * 16;
            float4 v = make_float4(0.f, 0.f, 0.f, 0.f);
            if (row < N_NODES)
                v = *reinterpret_cast<const float4*>(x + (size_t)row * D_IN + k);
            As[k + 0][m] = v.x;
            As[k + 1][m] = v.y;
            As[k + 2][m] = v.z;
            As[k + 3][m] = v.w;
        }
    }
    {
        const int n = t & 63;
        const int kbase = t >> 6;
        #pragma unroll
        for (int i = 0; i < 32; ++i) {
            const int k = kbase + i * 4;
            Bs[k][n] = W[(size_t)k * D_OUT + col0 + n];
        }
    }
    __syncthreads();

    const int tx = t & 15;
    const int ty = t >> 4;
    float acc[4][4];
    #pragma unroll
    for (int i = 0; i < 4; ++i)
        #pragma unroll
        for (int j = 0; j < 4; ++j) acc[i][j] = 0.f;

    #pragma unroll 8
    for (int k = 0; k < D_IN; ++k) {
        float4 a = *reinterpret_cast<const float4*>(&As[k][ty * 4]);
        float4 b = *reinterpret_cast<const float4*>(&Bs[k][tx * 4]);
        float av[4] = {a.x, a.y, a.z, a.w};
        float bv[4] = {b.x, b.y, b.z, b.w};
        #pragma unroll
        for (int i = 0; i < 4; ++i)
            #pragma unroll
            for (int j = 0; j < 4; ++j)
                acc[i][j] += av[i] * bv[j];
    }

    #pragma unroll
    for (int i = 0; i < 4; ++i) {
        const int row = row0 + ty * 4 + i;
        if (row >= N_NODES) continue;
        float4 o;
        o.x = fmaxf(acc[i][0], 0.f);
        o.y = fmaxf(acc[i][1], 0.f);
        o.z = fmaxf(acc[i][2], 0.f);
        o.w = fmaxf(acc[i][3], 0.f);
        *reinterpret_cast<float4*>(out + (size_t)row * D_OUT + col0 + tx * 4) = o;
    }
}

extern "C" void kernel_launch(void* const* d_in, const int* in_sizes, int n_in,
                              void* d_out, int out_size, void* d_ws, size_t ws_size,
                              hipStream_t stream) {
    const float* h  = (const float*)d_in[0];
    const int* esrc = (const int*)d_in[1];
    const int* edst = (const int*)d_in[2];
    const float* ew = (const float*)d_in[3];
    const float* Wn = (const float*)d_in[4];
    float* out = (float*)d_out;

    // workspace layout (4-byte units)
    float* x       = (float*)d_ws;                         // 6,400,000 f32
    int*   counts  = (int*)(x + (size_t)N_NODES * D_IN);   // 50,000
    int*   row_ptr = counts + N_NODES;                     // 50,001
    int*   cursor  = row_ptr + (N_NODES + 1);              // 50,000
    int*   srt_src = cursor + N_NODES;                     // 600,000
    float* srt_w   = (float*)(srt_src + N_EDGES);          // 600,000

    hipMemsetAsync(counts, 0, (size_t)N_NODES * sizeof(int), stream);

    const int eblocks = (N_EDGES + 255) / 256;
    hist_dst<<<eblocks, 256, 0, stream>>>(edst, counts);
    scan_counts<<<1, 1024, 0, stream>>>(counts, row_ptr, cursor);
    fill_csr<<<eblocks, 256, 0, stream>>>(esrc, edst, ew, cursor, srt_src, srt_w);
    gather_nodes<<<(N_NODES + 3) / 4, 256, 0, stream>>>(h, row_ptr, srt_src, srt_w, x);

    dim3 grid((N_NODES + BM - 1) / BM, D_OUT / BN);
    gemm_relu<<<grid, 256, 0, stream>>>(x, Wn, out);
}

// Round 3
// 197.438 us; speedup vs baseline: 5.4813x; 1.2261x over previous
//
#include <hip/hip_runtime.h>

#define N_NODES 50000
#define N_EDGES 600000
#define D_IN 128
#define D_OUT 256

typedef __attribute__((ext_vector_type(8))) short short8v;
typedef __attribute__((ext_vector_type(4))) float float4v;

__device__ inline unsigned bfbits(float f) {
    unsigned u = __float_as_uint(f);
    return (u + 0x7FFFu + ((u >> 16) & 1u)) >> 16;   // RNE f32 -> bf16 bits
}

// ---------- Stage 0: W[k][n] -> Wt_bf16[n][k] ----------
__global__ __launch_bounds__(256)
void convert_w(const float* __restrict__ W, unsigned short* __restrict__ wt) {
    const int k = blockIdx.x;     // 0..127
    const int n = threadIdx.x;    // 0..255
    wt[(size_t)n * D_IN + k] = (unsigned short)bfbits(W[(size_t)k * D_OUT + n]);
}

// ---------- Stage 1a: histogram of edge destinations ----------
__global__ __launch_bounds__(256)
void hist_dst(const int* __restrict__ edst, int* __restrict__ counts) {
    int e = blockIdx.x * 256 + threadIdx.x;
    if (e < N_EDGES) atomicAdd(&counts[edst[e]], 1);
}

// ---------- Stage 1b: exclusive prefix scan (single block, 1024 thr) ----------
__global__ __launch_bounds__(1024)
void scan_counts(const int* __restrict__ counts, int* __restrict__ row_ptr,
                 int* __restrict__ cursor) {
    __shared__ int wave_sums[16];
    __shared__ int wave_offs[16];
    __shared__ int s_total;
    const int t = threadIdx.x;
    const int lane = t & 63;
    const int wv = t >> 6;
    int running = 0;
    for (int base = 0; base < N_NODES; base += 1024) {
        const int idx = base + t;
        int v = (idx < N_NODES) ? counts[idx] : 0;
        int s = v;
        #pragma unroll
        for (int d = 1; d < 64; d <<= 1) {
            int u = __shfl_up(s, d, 64);
            if (lane >= d) s += u;
        }
        if (lane == 63) wave_sums[wv] = s;
        __syncthreads();
        if (wv == 0 && lane < 16) {
            int ws = wave_sums[lane];
            int inc = ws;
            #pragma unroll
            for (int d = 1; d < 16; d <<= 1) {
                int u = __shfl_up(inc, d, 64);
                if (lane >= d) inc += u;
            }
            wave_offs[lane] = inc - ws;
            if (lane == 15) s_total = inc;
        }
        __syncthreads();
        if (idx < N_NODES) {
            int excl = running + wave_offs[wv] + (s - v);
            row_ptr[idx] = excl;
            cursor[idx] = excl;
        }
        running += s_total;
    }
    if (t == 0) row_ptr[N_NODES] = running;
}

// ---------- Stage 1c: scatter edges into CSR slots (packed src+w) ----------
__global__ __launch_bounds__(256)
void fill_csr(const int* __restrict__ esrc, const int* __restrict__ edst,
              const float* __restrict__ ew, int* __restrict__ cursor,
              int2* __restrict__ srt) {
    int e = blockIdx.x * 256 + threadIdx.x;
    if (e >= N_EDGES) return;
    int d = edst[e];
    int p = atomicAdd(&cursor[d], 1);
    srt[p] = make_int2(esrc[e], __float_as_int(ew[e]));
}

// ---------- Stage 1d: gather-reduce, one wave per node, 4-deep MLP ----------
// Emits x directly as bf16 row-major [N_NODES][D_IN].
__global__ __launch_bounds__(256)
void gather_nodes(const float* __restrict__ h,
                  const int* __restrict__ row_ptr,
                  const int2* __restrict__ srt,
                  unsigned short* __restrict__ xb) {
    const int wv = threadIdx.x >> 6;
    const int lane = threadIdx.x & 63;
    const int n = blockIdx.x * 4 + wv;
    if (n >= N_NODES) return;
    const int beg = row_ptr[n];
    const int end = row_ptr[n + 1];
    const int l2 = lane * 2;
    float ax0 = 0.f, ay0 = 0.f, ax1 = 0.f, ay1 = 0.f;
    float ax2 = 0.f, ay2 = 0.f, ax3 = 0.f, ay3 = 0.f;
    int e = beg;
    for (; e + 4 <= end; e += 4) {
        int2 p0 = srt[e + 0], p1 = srt[e + 1], p2 = srt[e + 2], p3 = srt[e + 3];
        float2 v0 = *reinterpret_cast<const float2*>(h + (size_t)p0.x * D_IN + l2);
        float2 v1 = *reinterpret_cast<const float2*>(h + (size_t)p1.x * D_IN + l2);
        float2 v2 = *reinterpret_cast<const float2*>(h + (size_t)p2.x * D_IN + l2);
        float2 v3 = *reinterpret_cast<const float2*>(h + (size_t)p3.x * D_IN + l2);
        float w0 = __int_as_float(p0.y), w1 = __int_as_float(p1.y);
        float w2 = __int_as_float(p2.y), w3 = __int_as_float(p3.y);
        ax0 = fmaf(w0, v0.x, ax0); ay0 = fmaf(w0, v0.y, ay0);
        ax1 = fmaf(w1, v1.x, ax1); ay1 = fmaf(w1, v1.y, ay1);
        ax2 = fmaf(w2, v2.x, ax2); ay2 = fmaf(w2, v2.y, ay2);
        ax3 = fmaf(w3, v3.x, ax3); ay3 = fmaf(w3, v3.y, ay3);
    }
    for (; e < end; ++e) {
        int2 p = srt[e];
        float2 v = *reinterpret_cast<const float2*>(h + (size_t)p.x * D_IN + l2);
        float w = __int_as_float(p.y);
        ax0 = fmaf(w, v.x, ax0); ay0 = fmaf(w, v.y, ay0);
    }
    float sx = (ax0 + ax1) + (ax2 + ax3);
    float sy = (ay0 + ay1) + (ay2 + ay3);
    unsigned pack = bfbits(sx) | (bfbits(sy) << 16);
    *reinterpret_cast<unsigned*>(xb + (size_t)n * D_IN + l2) = pack;
}

// ---------- Stage 2: out = relu(x_bf16 @ Wt_bf16^T) via MFMA ----------
// One wave per 16-row strip; full N=256 (16 col-tiles); K=128 (4 mfma/tile).
// A/B frag: row(col)=lane&15, k=(lane>>4)*8+i. C: col=lane&15, row=(lane>>4)*4+q.
__global__ __launch_bounds__(256)
void gemm_mfma(const unsigned short* __restrict__ xb,
               const unsigned short* __restrict__ wt,
               float* __restrict__ out) {
    const int wv = threadIdx.x >> 6;
    const int lane = threadIdx.x & 63;
    const int row0 = blockIdx.x * 64 + wv * 16;
    if (row0 >= N_NODES) return;
    const int g = lane >> 4;
    const int r = lane & 15;

    short8v a[4];
    const unsigned short* arow = xb + (size_t)(row0 + r) * D_IN + g * 8;
    #pragma unroll
    for (int s = 0; s < 4; ++s)
        a[s] = *reinterpret_cast<const short8v*>(arow + 32 * s);

    #pragma unroll
    for (int t = 0; t < 16; ++t) {
        const unsigned short* brow = wt + (size_t)(t * 16 + r) * D_IN + g * 8;
        float4v acc = {0.f, 0.f, 0.f, 0.f};
        #pragma unroll
        for (int s = 0; s < 4; ++s) {
            short8v b = *reinterpret_cast<const short8v*>(brow + 32 * s);
            acc = __builtin_amdgcn_mfma_f32_16x16x32_bf16(a[s], b, acc, 0, 0, 0);
        }
        #pragma unroll
        for (int q = 0; q < 4; ++q) {
            out[(size_t)(row0 + g * 4 + q) * D_OUT + t * 16 + r] = fmaxf(acc[q], 0.f);
        }
    }
}

extern "C" void kernel_launch(void* const* d_in, const int* in_sizes, int n_in,
                              void* d_out, int out_size, void* d_ws, size_t ws_size,
                              hipStream_t stream) {
    const float* h  = (const float*)d_in[0];
    const int* esrc = (const int*)d_in[1];
    const int* edst = (const int*)d_in[2];
    const float* ew = (const float*)d_in[3];
    const float* Wn = (const float*)d_in[4];
    float* out = (float*)d_out;

    // workspace layout (byte offsets, all 16B-aligned)
    char* ws = (char*)d_ws;
    unsigned short* xb  = (unsigned short*)ws;                      // 12,800,000 B
    unsigned short* wt  = (unsigned short*)(ws + 12800000);         //     65,536 B
    int*   counts       = (int*)(ws + 12800000 + 65536);            //    200,000 B
    int*   row_ptr      = (int*)(ws + 13065536);                    //    200,016 B (50001 ints, padded)
    int*   cursor       = (int*)(ws + 13265552);                    //    200,000 B
    int2*  srt          = (int2*)(ws + 13465552);                   //  4,800,000 B

    convert_w<<<D_IN, 256, 0, stream>>>(Wn, wt);
    hipMemsetAsync(counts, 0, (size_t)N_NODES * sizeof(int), stream);

    const int eblocks = (N_EDGES + 255) / 256;
    hist_dst<<<eblocks, 256, 0, stream>>>(edst, counts);
    scan_counts<<<1, 1024, 0, stream>>>(counts, row_ptr, cursor);
    fill_csr<<<eblocks, 256, 0, stream>>>(esrc, edst, ew, cursor, srt);
    gather_nodes<<<(N_NODES + 3) / 4, 256, 0, stream>>>(h, row_ptr, srt, xb);

    gemm_mfma<<<(N_NODES + 63) / 64, 256, 0, stream>>>(xb, wt, out);
}

// Round 4
// 164.514 us; speedup vs baseline: 6.5783x; 1.2001x over previous
//
#include <hip/hip_runtime.h>

#define N_NODES 50000
#define N_EDGES 600000
#define D_IN 128
#define D_OUT 256

typedef __attribute__((ext_vector_type(8))) short short8v;
typedef __attribute__((ext_vector_type(4))) float float4v;

#define NB_CONVH 3125   // 256 thr * 8 f32 = 2048 elems/block; 6,400,000/2048
#define NB_HIST  586    // 256 thr * 4 edges = 1024/block; ceil(600,000/1024)
#define NB_CONVW 16     // 256 thr * 8 elems = 2048/block; 32,768/2048

__device__ inline unsigned bfbits(float f) {
    unsigned u = __float_as_uint(f);
    return (u + 0x7FFFu + ((u >> 16) & 1u)) >> 16;   // RNE f32 -> bf16 bits
}
__device__ inline unsigned pack2(float lo, float hi) {
    return bfbits(lo) | (bfbits(hi) << 16);
}

// ---------- Stage 0 (fused): h->bf16, dst histogram, W->Wt bf16 ----------
__global__ __launch_bounds__(256)
void prep(const float* __restrict__ h, unsigned short* __restrict__ hb,
          const int* __restrict__ edst, int* __restrict__ counts,
          const float* __restrict__ W, unsigned short* __restrict__ wt) {
    const int bid = blockIdx.x;
    const int t = threadIdx.x;
    if (bid < NB_CONVH) {
        // h[idx0..idx0+7] f32 -> bf16
        const size_t idx0 = ((size_t)bid * 256 + t) * 8;
        float4 a = *reinterpret_cast<const float4*>(h + idx0);
        float4 b = *reinterpret_cast<const float4*>(h + idx0 + 4);
        uint4 o;
        o.x = pack2(a.x, a.y);
        o.y = pack2(a.z, a.w);
        o.z = pack2(b.x, b.y);
        o.w = pack2(b.z, b.w);
        *reinterpret_cast<uint4*>(hb + idx0) = o;
    } else if (bid < NB_CONVH + NB_HIST) {
        const int e0 = ((bid - NB_CONVH) * 256 + t) * 4;
        if (e0 < N_EDGES) {   // 600000 % 4 == 0 -> groups fully in/out
            int4 d = *reinterpret_cast<const int4*>(edst + e0);
            atomicAdd(&counts[d.x], 1);
            atomicAdd(&counts[d.y], 1);
            atomicAdd(&counts[d.z], 1);
            atomicAdd(&counts[d.w], 1);
        }
    } else {
        // wt[n][k0..k0+7] = W[k0..k0+7][n]
        const int tid = (bid - NB_CONVH - NB_HIST) * 256 + t;
        const int n = tid >> 4;
        const int k0 = (tid & 15) * 8;
        uint4 o;
        o.x = pack2(W[(size_t)(k0 + 0) * D_OUT + n], W[(size_t)(k0 + 1) * D_OUT + n]);
        o.y = pack2(W[(size_t)(k0 + 2) * D_OUT + n], W[(size_t)(k0 + 3) * D_OUT + n]);
        o.z = pack2(W[(size_t)(k0 + 4) * D_OUT + n], W[(size_t)(k0 + 5) * D_OUT + n]);
        o.w = pack2(W[(size_t)(k0 + 6) * D_OUT + n], W[(size_t)(k0 + 7) * D_OUT + n]);
        *reinterpret_cast<uint4*>(wt + (size_t)n * D_IN + k0) = o;
    }
}

// ---------- Stage 1b: exclusive scan, 8 elems/thread, 7 iterations ----------
__global__ __launch_bounds__(1024)
void scan_counts(const int* __restrict__ counts, int* __restrict__ row_ptr,
                 int* __restrict__ cursor) {
    __shared__ int wave_sums[16];
    __shared__ int wave_offs[16];
    __shared__ int s_total;
    const int t = threadIdx.x;
    const int lane = t & 63;
    const int wv = t >> 6;
    int running = 0;
    for (int base = 0; base < N_NODES; base += 8192) {
        const int i0 = base + t * 8;
        int v[8];
        if (i0 < N_NODES) {   // 50000 % 8 == 0 -> groups fully in/out
            int4 a = *reinterpret_cast<const int4*>(counts + i0);
            int4 b = *reinterpret_cast<const int4*>(counts + i0 + 4);
            v[0] = a.x; v[1] = a.y; v[2] = a.z; v[3] = a.w;
            v[4] = b.x; v[5] = b.y; v[6] = b.z; v[7] = b.w;
        } else {
            #pragma unroll
            for (int j = 0; j < 8; ++j) v[j] = 0;
        }
        int s[8];
        s[0] = v[0];
        #pragma unroll
        for (int j = 1; j < 8; ++j) s[j] = s[j - 1] + v[j];
        const int tot = s[7];
        int ws = tot;
        #pragma unroll
        for (int d = 1; d < 64; d <<= 1) {
            int u = __shfl_up(ws, d, 64);
            if (lane >= d) ws += u;
        }
        const int texcl = ws - tot;
        if (lane == 63) wave_sums[wv] = ws;
        __syncthreads();
        if (wv == 0 && lane < 16) {
            int w0 = wave_sums[lane];
            int inc = w0;
            #pragma unroll
            for (int d = 1; d < 16; d <<= 1) {
                int u = __shfl_up(inc, d, 64);
                if (lane >= d) inc += u;
            }
            wave_offs[lane] = inc - w0;
            if (lane == 15) s_total = inc;
        }
        __syncthreads();
        if (i0 < N_NODES) {
            const int eb = running + wave_offs[wv] + texcl;
            int4 o1 = make_int4(eb, eb + s[0], eb + s[1], eb + s[2]);
            int4 o2 = make_int4(eb + s[3], eb + s[4], eb + s[5], eb + s[6]);
            *reinterpret_cast<int4*>(row_ptr + i0) = o1;
            *reinterpret_cast<int4*>(row_ptr + i0 + 4) = o2;
            *reinterpret_cast<int4*>(cursor + i0) = o1;
            *reinterpret_cast<int4*>(cursor + i0 + 4) = o2;
        }
        running += s_total;
    }
    if (t == 0) row_ptr[N_NODES] = running;
}

// ---------- Stage 1c: scatter edges into CSR slots (4 edges/thread) ----------
__global__ __launch_bounds__(256)
void fill_csr(const int* __restrict__ esrc, const int* __restrict__ edst,
              const float* __restrict__ ew, int* __restrict__ cursor,
              int2* __restrict__ srt) {
    const int e0 = (blockIdx.x * 256 + threadIdx.x) * 4;
    if (e0 >= N_EDGES) return;
    int4 s = *reinterpret_cast<const int4*>(esrc + e0);
    int4 d = *reinterpret_cast<const int4*>(edst + e0);
    float4 w = *reinterpret_cast<const float4*>(ew + e0);
    int p0 = atomicAdd(&cursor[d.x], 1);
    srt[p0] = make_int2(s.x, __float_as_int(w.x));
    int p1 = atomicAdd(&cursor[d.y], 1);
    srt[p1] = make_int2(s.y, __float_as_int(w.y));
    int p2 = atomicAdd(&cursor[d.z], 1);
    srt[p2] = make_int2(s.z, __float_as_int(w.z));
    int p3 = atomicAdd(&cursor[d.w], 1);
    srt[p3] = make_int2(s.w, __float_as_int(w.w));
}

// ---------- Stage 1d: gather-reduce, wave/node, 2 edges/iter, 8 in flight ----
__global__ __launch_bounds__(256)
void gather_nodes(const unsigned short* __restrict__ hb,
                  const int* __restrict__ row_ptr,
                  const int2* __restrict__ srt,
                  unsigned short* __restrict__ xb) {
    const int wv = threadIdx.x >> 6;
    const int lane = threadIdx.x & 63;
    const int n = blockIdx.x * 4 + wv;
    if (n >= N_NODES) return;
    const int beg = row_ptr[n];
    const int end = row_ptr[n + 1];
    const int half = lane >> 5;       // which edge of the pair
    const int sl = lane & 31;         // 4 dims per lane: sl*4 .. sl*4+3
    float4 acc[4];
    #pragma unroll
    for (int i = 0; i < 4; ++i) acc[i] = make_float4(0.f, 0.f, 0.f, 0.f);

    int e = beg;
    for (; e + 8 <= end; e += 8) {
        #pragma unroll
        for (int i = 0; i < 4; ++i) {
            int2 p = srt[e + 2 * i + half];
            uint2 hv = *reinterpret_cast<const uint2*>(hb + (size_t)p.x * D_IN + sl * 4);
            float w = __int_as_float(p.y);
            float f0 = __uint_as_float(hv.x << 16);
            float f1 = __uint_as_float(hv.x & 0xFFFF0000u);
            float f2 = __uint_as_float(hv.y << 16);
            float f3 = __uint_as_float(hv.y & 0xFFFF0000u);
            acc[i].x = fmaf(w, f0, acc[i].x);
            acc[i].y = fmaf(w, f1, acc[i].y);
            acc[i].z = fmaf(w, f2, acc[i].z);
            acc[i].w = fmaf(w, f3, acc[i].w);
        }
    }
    for (; e + 2 <= end; e += 2) {
        int2 p = srt[e + half];
        uint2 hv = *reinterpret_cast<const uint2*>(hb + (size_t)p.x * D_IN + sl * 4);
        float w = __int_as_float(p.y);
        acc[0].x = fmaf(w, __uint_as_float(hv.x << 16), acc[0].x);
        acc[0].y = fmaf(w, __uint_as_float(hv.x & 0xFFFF0000u), acc[0].y);
        acc[0].z = fmaf(w, __uint_as_float(hv.y << 16), acc[0].z);
        acc[0].w = fmaf(w, __uint_as_float(hv.y & 0xFFFF0000u), acc[0].w);
    }
    if (e < end && half == 0) {   // odd leftover edge, half 0 only
        int2 p = srt[e];
        uint2 hv = *reinterpret_cast<const uint2*>(hb + (size_t)p.x * D_IN + sl * 4);
        float w = __int_as_float(p.y);
        acc[1].x = fmaf(w, __uint_as_float(hv.x << 16), acc[1].x);
        acc[1].y = fmaf(w, __uint_as_float(hv.x & 0xFFFF0000u), acc[1].y);
        acc[1].z = fmaf(w, __uint_as_float(hv.y << 16), acc[1].z);
        acc[1].w = fmaf(w, __uint_as_float(hv.y & 0xFFFF0000u), acc[1].w);
    }
    float4 sum;
    sum.x = (acc[0].x + acc[1].x) + (acc[2].x + acc[3].x);
    sum.y = (acc[0].y + acc[1].y) + (acc[2].y + acc[3].y);
    sum.z = (acc[0].z + acc[1].z) + (acc[2].z + acc[3].z);
    sum.w = (acc[0].w + acc[1].w) + (acc[2].w + acc[3].w);
    sum.x += __shfl_xor(sum.x, 32, 64);
    sum.y += __shfl_xor(sum.y, 32, 64);
    sum.z += __shfl_xor(sum.z, 32, 64);
    sum.w += __shfl_xor(sum.w, 32, 64);
    if (half == 0) {
        uint2 o;
        o.x = pack2(sum.x, sum.y);
        o.y = pack2(sum.z, sum.w);
        *reinterpret_cast<uint2*>(xb + (size_t)n * D_IN + sl * 4) = o;
    }
}

// ---------- Stage 2: out = relu(x_bf16 @ Wt^T) via MFMA ----------
__global__ __launch_bounds__(256)
void gemm_mfma(const unsigned short* __restrict__ xb,
               const unsigned short* __restrict__ wt,
               float* __restrict__ out) {
    const int wv = threadIdx.x >> 6;
    const int lane = threadIdx.x & 63;
    const int row0 = blockIdx.x * 64 + wv * 16;
    if (row0 >= N_NODES) return;
    const int g = lane >> 4;
    const int r = lane & 15;

    short8v a[4];
    const unsigned short* arow = xb + (size_t)(row0 + r) * D_IN + g * 8;
    #pragma unroll
    for (int s = 0; s < 4; ++s)
        a[s] = *reinterpret_cast<const short8v*>(arow + 32 * s);

    #pragma unroll
    for (int t = 0; t < 16; ++t) {
        const unsigned short* brow = wt + (size_t)(t * 16 + r) * D_IN + g * 8;
        float4v acc = {0.f, 0.f, 0.f, 0.f};
        #pragma unroll
        for (int s = 0; s < 4; ++s) {
            short8v b = *reinterpret_cast<const short8v*>(brow + 32 * s);
            acc = __builtin_amdgcn_mfma_f32_16x16x32_bf16(a[s], b, acc, 0, 0, 0);
        }
        #pragma unroll
        for (int q = 0; q < 4; ++q) {
            out[(size_t)(row0 + g * 4 + q) * D_OUT + t * 16 + r] = fmaxf(acc[q], 0.f);
        }
    }
}

extern "C" void kernel_launch(void* const* d_in, const int* in_sizes, int n_in,
                              void* d_out, int out_size, void* d_ws, size_t ws_size,
                              hipStream_t stream) {
    const float* h  = (const float*)d_in[0];
    const int* esrc = (const int*)d_in[1];
    const int* edst = (const int*)d_in[2];
    const float* ew = (const float*)d_in[3];
    const float* Wn = (const float*)d_in[4];
    float* out = (float*)d_out;

    // workspace layout (byte offsets, all 16B-aligned)
    char* ws = (char*)d_ws;
    unsigned short* hb  = (unsigned short*)(ws);                //  0        12,800,000 B
    unsigned short* xb  = (unsigned short*)(ws + 12800000);     //           12,800,000 B
    unsigned short* wt  = (unsigned short*)(ws + 25600000);     //               65,536 B
    int*   counts       = (int*)(ws + 25665536);                //              200,000 B
    int*   row_ptr      = (int*)(ws + 25865536);                //              200,032 B (50001 ints, padded)
    int*   cursor       = (int*)(ws + 26065568);                //              200,000 B
    int2*  srt          = (int2*)(ws + 26265568);               //            4,800,000 B
    // total 31,065,568 B

    hipMemsetAsync(counts, 0, (size_t)N_NODES * sizeof(int), stream);

    prep<<<NB_CONVH + NB_HIST + NB_CONVW, 256, 0, stream>>>(h, hb, edst, counts, Wn, wt);
    scan_counts<<<1, 1024, 0, stream>>>(counts, row_ptr, cursor);
    const int fblocks = (N_EDGES / 4 + 255) / 256;
    fill_csr<<<fblocks, 256, 0, stream>>>(esrc, edst, ew, cursor, srt);
    gather_nodes<<<(N_NODES + 3) / 4, 256, 0, stream>>>(hb, row_ptr, srt, xb);
    gemm_mfma<<<(N_NODES + 63) / 64, 256, 0, stream>>>(xb, wt, out);
}

// Round 5
// 159.872 us; speedup vs baseline: 6.7693x; 1.0290x over previous
//
#include <hip/hip_runtime.h>

#define N_NODES 50000
#define N_EDGES 600000
#define D_IN 128
#define D_OUT 256

typedef __attribute__((ext_vector_type(8))) short short8v;
typedef __attribute__((ext_vector_type(4))) float float4v;

#define NB_HIST  586    // 256 thr * 4 edges; FIRST so atomics overlap streaming
#define NB_CONVH 1563   // 256 thr * 16 f32 = 4096 elems/block
#define NB_CONVW 16     // 256 thr * 8 elems

__device__ inline unsigned bfbits(float f) {
    unsigned u = __float_as_uint(f);
    return (u + 0x7FFFu + ((u >> 16) & 1u)) >> 16;   // RNE f32 -> bf16 bits
}
__device__ inline unsigned pack2(float lo, float hi) {
    return bfbits(lo) | (bfbits(hi) << 16);
}

// ---------- Stage -1: zero the counts array ----------
__global__ __launch_bounds__(256)
void zero_counts(int4* __restrict__ counts4) {
    const int i = blockIdx.x * 256 + threadIdx.x;
    if (i < N_NODES / 4) counts4[i] = make_int4(0, 0, 0, 0);
}

// ---------- Stage 0 (fused): dst histogram, h->bf16, W->Wt bf16 ----------
__global__ __launch_bounds__(256)
void prep(const float* __restrict__ h, unsigned short* __restrict__ hb,
          const int* __restrict__ edst, int* __restrict__ counts,
          const float* __restrict__ W, unsigned short* __restrict__ wt) {
    const int bid = blockIdx.x;
    const int t = threadIdx.x;
    if (bid < NB_HIST) {
        const int e0 = (bid * 256 + t) * 4;
        if (e0 < N_EDGES) {   // 600000 % 4 == 0 -> groups fully in/out
            int4 d = *reinterpret_cast<const int4*>(edst + e0);
            atomicAdd(&counts[d.x], 1);
            atomicAdd(&counts[d.y], 1);
            atomicAdd(&counts[d.z], 1);
            atomicAdd(&counts[d.w], 1);
        }
    } else if (bid < NB_HIST + NB_CONVH) {
        const size_t idx0 = ((size_t)(bid - NB_HIST) * 256 + t) * 16;
        if (idx0 < (size_t)N_NODES * D_IN) {   // multiple of 16 -> full/none
            float4 a = *reinterpret_cast<const float4*>(h + idx0);
            float4 b = *reinterpret_cast<const float4*>(h + idx0 + 4);
            float4 c = *reinterpret_cast<const float4*>(h + idx0 + 8);
            float4 d = *reinterpret_cast<const float4*>(h + idx0 + 12);
            uint4 o1, o2;
            o1.x = pack2(a.x, a.y); o1.y = pack2(a.z, a.w);
            o1.z = pack2(b.x, b.y); o1.w = pack2(b.z, b.w);
            o2.x = pack2(c.x, c.y); o2.y = pack2(c.z, c.w);
            o2.z = pack2(d.x, d.y); o2.w = pack2(d.z, d.w);
            *reinterpret_cast<uint4*>(hb + idx0) = o1;
            *reinterpret_cast<uint4*>(hb + idx0 + 8) = o2;
        }
    } else {
        const int tid = (bid - NB_HIST - NB_CONVH) * 256 + t;
        const int n = tid >> 4;
        const int k0 = (tid & 15) * 8;
        uint4 o;
        o.x = pack2(W[(size_t)(k0 + 0) * D_OUT + n], W[(size_t)(k0 + 1) * D_OUT + n]);
        o.y = pack2(W[(size_t)(k0 + 2) * D_OUT + n], W[(size_t)(k0 + 3) * D_OUT + n]);
        o.z = pack2(W[(size_t)(k0 + 4) * D_OUT + n], W[(size_t)(k0 + 5) * D_OUT + n]);
        o.w = pack2(W[(size_t)(k0 + 6) * D_OUT + n], W[(size_t)(k0 + 7) * D_OUT + n]);
        *reinterpret_cast<uint4*>(wt + (size_t)n * D_IN + k0) = o;
    }
}

// ---------- Stage 1b: exclusive scan, 8 elems/thread ----------
__global__ __launch_bounds__(1024)
void scan_counts(const int* __restrict__ counts, int* __restrict__ row_ptr,
                 int* __restrict__ cursor) {
    __shared__ int wave_sums[16];
    __shared__ int wave_offs[16];
    __shared__ int s_total;
    const int t = threadIdx.x;
    const int lane = t & 63;
    const int wv = t >> 6;
    int running = 0;
    for (int base = 0; base < N_NODES; base += 8192) {
        const int i0 = base + t * 8;
        int v[8];
        if (i0 < N_NODES) {
            int4 a = *reinterpret_cast<const int4*>(counts + i0);
            int4 b = *reinterpret_cast<const int4*>(counts + i0 + 4);
            v[0] = a.x; v[1] = a.y; v[2] = a.z; v[3] = a.w;
            v[4] = b.x; v[5] = b.y; v[6] = b.z; v[7] = b.w;
        } else {
            #pragma unroll
            for (int j = 0; j < 8; ++j) v[j] = 0;
        }
        int s[8];
        s[0] = v[0];
        #pragma unroll
        for (int j = 1; j < 8; ++j) s[j] = s[j - 1] + v[j];
        const int tot = s[7];
        int ws = tot;
        #pragma unroll
        for (int d = 1; d < 64; d <<= 1) {
            int u = __shfl_up(ws, d, 64);
            if (lane >= d) ws += u;
        }
        const int texcl = ws - tot;
        if (lane == 63) wave_sums[wv] = ws;
        __syncthreads();
        if (wv == 0 && lane < 16) {
            int w0 = wave_sums[lane];
            int inc = w0;
            #pragma unroll
            for (int d = 1; d < 16; d <<= 1) {
                int u = __shfl_up(inc, d, 64);
                if (lane >= d) inc += u;
            }
            wave_offs[lane] = inc - w0;
            if (lane == 15) s_total = inc;
        }
        __syncthreads();
        if (i0 < N_NODES) {
            const int eb = running + wave_offs[wv] + texcl;
            int4 o1 = make_int4(eb, eb + s[0], eb + s[1], eb + s[2]);
            int4 o2 = make_int4(eb + s[3], eb + s[4], eb + s[5], eb + s[6]);
            *reinterpret_cast<int4*>(row_ptr + i0) = o1;
            *reinterpret_cast<int4*>(row_ptr + i0 + 4) = o2;
            *reinterpret_cast<int4*>(cursor + i0) = o1;
            *reinterpret_cast<int4*>(cursor + i0 + 4) = o2;
        }
        running += s_total;
    }
    if (t == 0) row_ptr[N_NODES] = running;
}

// ---------- Stage 1c: scatter edges into CSR slots ----------
__global__ __launch_bounds__(256)
void fill_csr(const int* __restrict__ esrc, const int* __restrict__ edst,
              const float* __restrict__ ew, int* __restrict__ cursor,
              int2* __restrict__ srt) {
    const int e0 = (blockIdx.x * 256 + threadIdx.x) * 4;
    if (e0 >= N_EDGES) return;
    int4 s = *reinterpret_cast<const int4*>(esrc + e0);
    int4 d = *reinterpret_cast<const int4*>(edst + e0);
    float4 w = *reinterpret_cast<const float4*>(ew + e0);
    int p0 = atomicAdd(&cursor[d.x], 1);
    srt[p0] = make_int2(s.x, __float_as_int(w.x));
    int p1 = atomicAdd(&cursor[d.y], 1);
    srt[p1] = make_int2(s.y, __float_as_int(w.y));
    int p2 = atomicAdd(&cursor[d.z], 1);
    srt[p2] = make_int2(s.z, __float_as_int(w.z));
    int p3 = atomicAdd(&cursor[d.w], 1);
    srt[p3] = make_int2(s.w, __float_as_int(w.w));
}

// ---------- Stage 2 (fused): gather 16 nodes into LDS, then MFMA strip ----
// Block = 16 nodes. Wave wv gathers nodes blk*16+wv*4+i (i=0..3) exactly as
// the R4 gather (2 edges/iter, 8 in flight), writes bf16 rows to LDS.
// Then all 4 waves compute out[16 x 256]: wave wv owns cols wv*64..wv*64+63.
__global__ __launch_bounds__(256)
void gather_gemm(const unsigned short* __restrict__ hb,
                 const int* __restrict__ row_ptr,
                 const int2* __restrict__ srt,
                 const unsigned short* __restrict__ wt,
                 float* __restrict__ out) {
    __shared__ unsigned short xlds[16 * 136];   // 16 rows, stride 136 shorts
    const int wv = threadIdx.x >> 6;
    const int lane = threadIdx.x & 63;
    const int half = lane >> 5;
    const int sl = lane & 31;
    const int nbase = blockIdx.x * 16 + wv * 4;

    #pragma unroll
    for (int i = 0; i < 4; ++i) {
        const int n = nbase + i;          // grid sized exactly: 3125*16 = 50000
        const int beg = row_ptr[n];
        const int end = row_ptr[n + 1];
        float4 acc[4];
        #pragma unroll
        for (int j = 0; j < 4; ++j) acc[j] = make_float4(0.f, 0.f, 0.f, 0.f);
        int e = beg;
        for (; e + 8 <= end; e += 8) {
            #pragma unroll
            for (int j = 0; j < 4; ++j) {
                int2 p = srt[e + 2 * j + half];
                uint2 hv = *reinterpret_cast<const uint2*>(hb + (size_t)p.x * D_IN + sl * 4);
                float w = __int_as_float(p.y);
                acc[j].x = fmaf(w, __uint_as_float(hv.x << 16), acc[j].x);
                acc[j].y = fmaf(w, __uint_as_float(hv.x & 0xFFFF0000u), acc[j].y);
                acc[j].z = fmaf(w, __uint_as_float(hv.y << 16), acc[j].z);
                acc[j].w = fmaf(w, __uint_as_float(hv.y & 0xFFFF0000u), acc[j].w);
            }
        }
        for (; e + 2 <= end; e += 2) {
            int2 p = srt[e + half];
            uint2 hv = *reinterpret_cast<const uint2*>(hb + (size_t)p.x * D_IN + sl * 4);
            float w = __int_as_float(p.y);
            acc[0].x = fmaf(w, __uint_as_float(hv.x << 16), acc[0].x);
            acc[0].y = fmaf(w, __uint_as_float(hv.x & 0xFFFF0000u), acc[0].y);
            acc[0].z = fmaf(w, __uint_as_float(hv.y << 16), acc[0].z);
            acc[0].w = fmaf(w, __uint_as_float(hv.y & 0xFFFF0000u), acc[0].w);
        }
        if (e < end && half == 0) {
            int2 p = srt[e];
            uint2 hv = *reinterpret_cast<const uint2*>(hb + (size_t)p.x * D_IN + sl * 4);
            float w = __int_as_float(p.y);
            acc[1].x = fmaf(w, __uint_as_float(hv.x << 16), acc[1].x);
            acc[1].y = fmaf(w, __uint_as_float(hv.x & 0xFFFF0000u), acc[1].y);
            acc[1].z = fmaf(w, __uint_as_float(hv.y << 16), acc[1].z);
            acc[1].w = fmaf(w, __uint_as_float(hv.y & 0xFFFF0000u), acc[1].w);
        }
        float4 sum;
        sum.x = (acc[0].x + acc[1].x) + (acc[2].x + acc[3].x);
        sum.y = (acc[0].y + acc[1].y) + (acc[2].y + acc[3].y);
        sum.z = (acc[0].z + acc[1].z) + (acc[2].z + acc[3].z);
        sum.w = (acc[0].w + acc[1].w) + (acc[2].w + acc[3].w);
        sum.x += __shfl_xor(sum.x, 32, 64);
        sum.y += __shfl_xor(sum.y, 32, 64);
        sum.z += __shfl_xor(sum.z, 32, 64);
        sum.w += __shfl_xor(sum.w, 32, 64);
        if (half == 0) {
            uint2 o;
            o.x = pack2(sum.x, sum.y);
            o.y = pack2(sum.z, sum.w);
            *reinterpret_cast<uint2*>(&xlds[(wv * 4 + i) * 136 + sl * 4]) = o;
        }
    }
    __syncthreads();

    // MFMA: A rows = block's 16 nodes (from LDS), B = wt cols wv*64.. .
    // A/B frag: row(col)=lane&15, k=(lane>>4)*8+i. C: col=lane&15, row=g*4+q.
    const int g = lane >> 4;
    const int r = lane & 15;
    short8v a[4];
    const unsigned short* ar = &xlds[r * 136 + g * 8];
    #pragma unroll
    for (int s = 0; s < 4; ++s)
        a[s] = *reinterpret_cast<const short8v*>(ar + 32 * s);

    const int row0 = blockIdx.x * 16;
    #pragma unroll
    for (int t2 = 0; t2 < 4; ++t2) {
        const int col0 = wv * 64 + t2 * 16;
        const unsigned short* brow = wt + (size_t)(col0 + r) * D_IN + g * 8;
        float4v acc = {0.f, 0.f, 0.f, 0.f};
        #pragma unroll
        for (int s = 0; s < 4; ++s) {
            short8v b = *reinterpret_cast<const short8v*>(brow + 32 * s);
            acc = __builtin_amdgcn_mfma_f32_16x16x32_bf16(a[s], b, acc, 0, 0, 0);
        }
        #pragma unroll
        for (int q = 0; q < 4; ++q) {
            out[(size_t)(row0 + g * 4 + q) * D_OUT + col0 + r] = fmaxf(acc[q], 0.f);
        }
    }
}

extern "C" void kernel_launch(void* const* d_in, const int* in_sizes, int n_in,
                              void* d_out, int out_size, void* d_ws, size_t ws_size,
                              hipStream_t stream) {
    const float* h  = (const float*)d_in[0];
    const int* esrc = (const int*)d_in[1];
    const int* edst = (const int*)d_in[2];
    const float* ew = (const float*)d_in[3];
    const float* Wn = (const float*)d_in[4];
    float* out = (float*)d_out;

    // workspace layout (byte offsets, all 16B-aligned)
    char* ws = (char*)d_ws;
    unsigned short* hb  = (unsigned short*)(ws);                // 12,800,000 B
    unsigned short* wt  = (unsigned short*)(ws + 12800000);     //     65,536 B
    int*   counts       = (int*)(ws + 12865536);                //    200,000 B
    int*   row_ptr      = (int*)(ws + 13065536);                //    200,032 B
    int*   cursor       = (int*)(ws + 13265568);                //    200,000 B
    int2*  srt          = (int2*)(ws + 13465568);               //  4,800,000 B
    // total 18,265,568 B

    zero_counts<<<(N_NODES / 4 + 255) / 256, 256, 0, stream>>>((int4*)counts);
    prep<<<NB_HIST + NB_CONVH + NB_CONVW, 256, 0, stream>>>(h, hb, edst, counts, Wn, wt);
    scan_counts<<<1, 1024, 0, stream>>>(counts, row_ptr, cursor);
    const int fblocks = (N_EDGES / 4 + 255) / 256;
    fill_csr<<<fblocks, 256, 0, stream>>>(esrc, edst, ew, cursor, srt);
    gather_gemm<<<N_NODES / 16, 256, 0, stream>>>(hb, row_ptr, srt, wt, out);
}

// Round 6
// 154.007 us; speedup vs baseline: 7.0271x; 1.0381x over previous
//
#include <hip/hip_runtime.h>
#include <hip/hip_fp16.h>

#define N_NODES 50000
#define N_EDGES 600000
#define D_IN 128
#define D_OUT 256

typedef __attribute__((ext_vector_type(8))) short short8v;
typedef __attribute__((ext_vector_type(4))) float float4v;

#define NB_CONVH 1563   // 256 thr * 16 f32 = 4096 elems/block
#define NB_CONVW 16     // 256 thr * 8 elems
#define NB_ZERO  49     // 12500 int4 / 256

__device__ inline unsigned bfbits(float f) {
    unsigned u = __float_as_uint(f);
    return (u + 0x7FFFu + ((u >> 16) & 1u)) >> 16;   // RNE f32 -> bf16 bits
}
__device__ inline unsigned pack2(float lo, float hi) {
    return bfbits(lo) | (bfbits(hi) << 16);
}

// ---------- Stage 0: pure-streaming prep: h->bf16, W->Wt bf16, zero counts --
__global__ __launch_bounds__(256)
void prep_streams(const float* __restrict__ h, unsigned short* __restrict__ hb,
                  const float* __restrict__ W, unsigned short* __restrict__ wt,
                  int4* __restrict__ counts4) {
    const int bid = blockIdx.x;
    const int t = threadIdx.x;
    if (bid < NB_CONVH) {
        const size_t idx0 = ((size_t)bid * 256 + t) * 16;
        if (idx0 < (size_t)N_NODES * D_IN) {   // multiple of 16 -> full/none
            float4 a = *reinterpret_cast<const float4*>(h + idx0);
            float4 b = *reinterpret_cast<const float4*>(h + idx0 + 4);
            float4 c = *reinterpret_cast<const float4*>(h + idx0 + 8);
            float4 d = *reinterpret_cast<const float4*>(h + idx0 + 12);
            uint4 o1, o2;
            o1.x = pack2(a.x, a.y); o1.y = pack2(a.z, a.w);
            o1.z = pack2(b.x, b.y); o1.w = pack2(b.z, b.w);
            o2.x = pack2(c.x, c.y); o2.y = pack2(c.z, c.w);
            o2.z = pack2(d.x, d.y); o2.w = pack2(d.z, d.w);
            *reinterpret_cast<uint4*>(hb + idx0) = o1;
            *reinterpret_cast<uint4*>(hb + idx0 + 8) = o2;
        }
    } else if (bid < NB_CONVH + NB_CONVW) {
        const int tid = (bid - NB_CONVH) * 256 + t;
        const int n = tid >> 4;
        const int k0 = (tid & 15) * 8;
        uint4 o;
        o.x = pack2(W[(size_t)(k0 + 0) * D_OUT + n], W[(size_t)(k0 + 1) * D_OUT + n]);
        o.y = pack2(W[(size_t)(k0 + 2) * D_OUT + n], W[(size_t)(k0 + 3) * D_OUT + n]);
        o.z = pack2(W[(size_t)(k0 + 4) * D_OUT + n], W[(size_t)(k0 + 5) * D_OUT + n]);
        o.w = pack2(W[(size_t)(k0 + 6) * D_OUT + n], W[(size_t)(k0 + 7) * D_OUT + n]);
        *reinterpret_cast<uint4*>(wt + (size_t)n * D_IN + k0) = o;
    } else {
        const int i = (bid - NB_CONVH - NB_CONVW) * 256 + t;
        if (i < N_NODES / 4) counts4[i] = make_int4(0, 0, 0, 0);
    }
}

// ---------- Stage 1a: histogram of edge destinations (atomics only) --------
__global__ __launch_bounds__(256)
void hist_dst(const int* __restrict__ edst, int* __restrict__ counts) {
    const int e0 = (blockIdx.x * 256 + threadIdx.x) * 4;
    if (e0 < N_EDGES) {   // 600000 % 4 == 0
        int4 d = *reinterpret_cast<const int4*>(edst + e0);
        atomicAdd(&counts[d.x], 1);
        atomicAdd(&counts[d.y], 1);
        atomicAdd(&counts[d.z], 1);
        atomicAdd(&counts[d.w], 1);
    }
}

// ---------- Stage 1b: exclusive scan, 8 elems/thread ----------
__global__ __launch_bounds__(1024)
void scan_counts(const int* __restrict__ counts, int* __restrict__ row_ptr,
                 int* __restrict__ cursor) {
    __shared__ int wave_sums[16];
    __shared__ int wave_offs[16];
    __shared__ int s_total;
    const int t = threadIdx.x;
    const int lane = t & 63;
    const int wv = t >> 6;
    int running = 0;
    for (int base = 0; base < N_NODES; base += 8192) {
        const int i0 = base + t * 8;
        int v[8];
        if (i0 < N_NODES) {
            int4 a = *reinterpret_cast<const int4*>(counts + i0);
            int4 b = *reinterpret_cast<const int4*>(counts + i0 + 4);
            v[0] = a.x; v[1] = a.y; v[2] = a.z; v[3] = a.w;
            v[4] = b.x; v[5] = b.y; v[6] = b.z; v[7] = b.w;
        } else {
            #pragma unroll
            for (int j = 0; j < 8; ++j) v[j] = 0;
        }
        int s[8];
        s[0] = v[0];
        #pragma unroll
        for (int j = 1; j < 8; ++j) s[j] = s[j - 1] + v[j];
        const int tot = s[7];
        int ws = tot;
        #pragma unroll
        for (int d = 1; d < 64; d <<= 1) {
            int u = __shfl_up(ws, d, 64);
            if (lane >= d) ws += u;
        }
        const int texcl = ws - tot;
        if (lane == 63) wave_sums[wv] = ws;
        __syncthreads();
        if (wv == 0 && lane < 16) {
            int w0 = wave_sums[lane];
            int inc = w0;
            #pragma unroll
            for (int d = 1; d < 16; d <<= 1) {
                int u = __shfl_up(inc, d, 64);
                if (lane >= d) inc += u;
            }
            wave_offs[lane] = inc - w0;
            if (lane == 15) s_total = inc;
        }
        __syncthreads();
        if (i0 < N_NODES) {
            const int eb = running + wave_offs[wv] + texcl;
            int4 o1 = make_int4(eb, eb + s[0], eb + s[1], eb + s[2]);
            int4 o2 = make_int4(eb + s[3], eb + s[4], eb + s[5], eb + s[6]);
            *reinterpret_cast<int4*>(row_ptr + i0) = o1;
            *reinterpret_cast<int4*>(row_ptr + i0 + 4) = o2;
            *reinterpret_cast<int4*>(cursor + i0) = o1;
            *reinterpret_cast<int4*>(cursor + i0 + 4) = o2;
        }
        running += s_total;
    }
    if (t == 0) row_ptr[N_NODES] = running;
}

// ---------- Stage 1c: scatter edges into CSR slots, 4B packed entries ------
// entry = (fp16(weight) << 16) | src   (src < 50000 < 2^16)
__global__ __launch_bounds__(256)
void fill_csr(const int* __restrict__ esrc, const int* __restrict__ edst,
              const float* __restrict__ ew, int* __restrict__ cursor,
              unsigned* __restrict__ srt) {
    const int e0 = (blockIdx.x * 256 + threadIdx.x) * 4;
    if (e0 >= N_EDGES) return;
    int4 s = *reinterpret_cast<const int4*>(esrc + e0);
    int4 d = *reinterpret_cast<const int4*>(edst + e0);
    float4 w = *reinterpret_cast<const float4*>(ew + e0);
    int p0 = atomicAdd(&cursor[d.x], 1);
    srt[p0] = ((unsigned)__half_as_ushort(__float2half(w.x)) << 16) | (unsigned)s.x;
    int p1 = atomicAdd(&cursor[d.y], 1);
    srt[p1] = ((unsigned)__half_as_ushort(__float2half(w.y)) << 16) | (unsigned)s.y;
    int p2 = atomicAdd(&cursor[d.z], 1);
    srt[p2] = ((unsigned)__half_as_ushort(__float2half(w.z)) << 16) | (unsigned)s.z;
    int p3 = atomicAdd(&cursor[d.w], 1);
    srt[p3] = ((unsigned)__half_as_ushort(__float2half(w.w)) << 16) | (unsigned)s.w;
}

// ---------- Stage 1d: gather-reduce, 1 node/wave, 2 edges/iter, 8 in flight -
__global__ __launch_bounds__(256)
void gather_nodes(const unsigned short* __restrict__ hb,
                  const int* __restrict__ row_ptr,
                  const unsigned* __restrict__ srt,
                  unsigned short* __restrict__ xb) {
    const int wv = threadIdx.x >> 6;
    const int lane = threadIdx.x & 63;
    const int n = blockIdx.x * 4 + wv;
    if (n >= N_NODES) return;
    const int beg = row_ptr[n];
    const int end = row_ptr[n + 1];
    const int half = lane >> 5;       // which edge of the pair
    const int sl = lane & 31;         // 4 dims per lane
    float4 acc[4];
    #pragma unroll
    for (int i = 0; i < 4; ++i) acc[i] = make_float4(0.f, 0.f, 0.f, 0.f);

    int e = beg;
    for (; e + 8 <= end; e += 8) {
        #pragma unroll
        for (int i = 0; i < 4; ++i) {
            unsigned p = srt[e + 2 * i + half];
            uint2 hv = *reinterpret_cast<const uint2*>(hb + (size_t)(p & 0xFFFFu) * D_IN + sl * 4);
            float w = __half2float(__ushort_as_half((unsigned short)(p >> 16)));
            acc[i].x = fmaf(w, __uint_as_float(hv.x << 16), acc[i].x);
            acc[i].y = fmaf(w, __uint_as_float(hv.x & 0xFFFF0000u), acc[i].y);
            acc[i].z = fmaf(w, __uint_as_float(hv.y << 16), acc[i].z);
            acc[i].w = fmaf(w, __uint_as_float(hv.y & 0xFFFF0000u), acc[i].w);
        }
    }
    for (; e + 2 <= end; e += 2) {
        unsigned p = srt[e + half];
        uint2 hv = *reinterpret_cast<const uint2*>(hb + (size_t)(p & 0xFFFFu) * D_IN + sl * 4);
        float w = __half2float(__ushort_as_half((unsigned short)(p >> 16)));
        acc[0].x = fmaf(w, __uint_as_float(hv.x << 16), acc[0].x);
        acc[0].y = fmaf(w, __uint_as_float(hv.x & 0xFFFF0000u), acc[0].y);
        acc[0].z = fmaf(w, __uint_as_float(hv.y << 16), acc[0].z);
        acc[0].w = fmaf(w, __uint_as_float(hv.y & 0xFFFF0000u), acc[0].w);
    }
    if (e < end && half == 0) {
        unsigned p = srt[e];
        uint2 hv = *reinterpret_cast<const uint2*>(hb + (size_t)(p & 0xFFFFu) * D_IN + sl * 4);
        float w = __half2float(__ushort_as_half((unsigned short)(p >> 16)));
        acc[1].x = fmaf(w, __uint_as_float(hv.x << 16), acc[1].x);
        acc[1].y = fmaf(w, __uint_as_float(hv.x & 0xFFFF0000u), acc[1].y);
        acc[1].z = fmaf(w, __uint_as_float(hv.y << 16), acc[1].z);
        acc[1].w = fmaf(w, __uint_as_float(hv.y & 0xFFFF0000u), acc[1].w);
    }
    float4 sum;
    sum.x = (acc[0].x + acc[1].x) + (acc[2].x + acc[3].x);
    sum.y = (acc[0].y + acc[1].y) + (acc[2].y + acc[3].y);
    sum.z = (acc[0].z + acc[1].z) + (acc[2].z + acc[3].z);
    sum.w = (acc[0].w + acc[1].w) + (acc[2].w + acc[3].w);
    sum.x += __shfl_xor(sum.x, 32, 64);
    sum.y += __shfl_xor(sum.y, 32, 64);
    sum.z += __shfl_xor(sum.z, 32, 64);
    sum.w += __shfl_xor(sum.w, 32, 64);
    if (half == 0) {
        uint2 o;
        o.x = pack2(sum.x, sum.y);
        o.y = pack2(sum.z, sum.w);
        *reinterpret_cast<uint2*>(xb + (size_t)n * D_IN + sl * 4) = o;
    }
}

// ---------- Stage 2: out = relu(x_bf16 @ Wt^T) via MFMA ----------
__global__ __launch_bounds__(256)
void gemm_mfma(const unsigned short* __restrict__ xb,
               const unsigned short* __restrict__ wt,
               float* __restrict__ out) {
    const int wv = threadIdx.x >> 6;
    const int lane = threadIdx.x & 63;
    const int row0 = blockIdx.x * 64 + wv * 16;
    if (row0 >= N_NODES) return;
    const int g = lane >> 4;
    const int r = lane & 15;

    short8v a[4];
    const unsigned short* arow = xb + (size_t)(row0 + r) * D_IN + g * 8;
    #pragma unroll
    for (int s = 0; s < 4; ++s)
        a[s] = *reinterpret_cast<const short8v*>(arow + 32 * s);

    #pragma unroll
    for (int t = 0; t < 16; ++t) {
        const unsigned short* brow = wt + (size_t)(t * 16 + r) * D_IN + g * 8;
        float4v acc = {0.f, 0.f, 0.f, 0.f};
        #pragma unroll
        for (int s = 0; s < 4; ++s) {
            short8v b = *reinterpret_cast<const short8v*>(brow + 32 * s);
            acc = __builtin_amdgcn_mfma_f32_16x16x32_bf16(a[s], b, acc, 0, 0, 0);
        }
        #pragma unroll
        for (int q = 0; q < 4; ++q) {
            out[(size_t)(row0 + g * 4 + q) * D_OUT + t * 16 + r] = fmaxf(acc[q], 0.f);
        }
    }
}

extern "C" void kernel_launch(void* const* d_in, const int* in_sizes, int n_in,
                              void* d_out, int out_size, void* d_ws, size_t ws_size,
                              hipStream_t stream) {
    const float* h  = (const float*)d_in[0];
    const int* esrc = (const int*)d_in[1];
    const int* edst = (const int*)d_in[2];
    const float* ew = (const float*)d_in[3];
    const float* Wn = (const float*)d_in[4];
    float* out = (float*)d_out;

    // workspace layout (byte offsets, all 16B-aligned)
    char* ws = (char*)d_ws;
    unsigned short* hb  = (unsigned short*)(ws);                // 12,800,000 B
    unsigned short* xb  = (unsigned short*)(ws + 12800000);     // 12,800,000 B
    unsigned short* wt  = (unsigned short*)(ws + 25600000);     //     65,536 B
    int*   counts       = (int*)(ws + 25665536);                //    200,000 B
    int*   row_ptr      = (int*)(ws + 25865536);                //    200,032 B
    int*   cursor       = (int*)(ws + 26065568);                //    200,000 B
    unsigned* srt       = (unsigned*)(ws + 26265568);           //  2,400,000 B
    // total 28,665,568 B

    prep_streams<<<NB_CONVH + NB_CONVW + NB_ZERO, 256, 0, stream>>>(h, hb, Wn, wt, (int4*)counts);
    const int eblocks = (N_EDGES / 4 + 255) / 256;
    hist_dst<<<eblocks, 256, 0, stream>>>(edst, counts);
    scan_counts<<<1, 1024, 0, stream>>>(counts, row_ptr, cursor);
    fill_csr<<<eblocks, 256, 0, stream>>>(esrc, edst, ew, cursor, srt);
    gather_nodes<<<(N_NODES + 3) / 4, 256, 0, stream>>>(hb, row_ptr, srt, xb);
    gemm_mfma<<<(N_NODES + 63) / 64, 256, 0, stream>>>(xb, wt, out);
}

// Round 7
// 153.263 us; speedup vs baseline: 7.0612x; 1.0049x over previous
//
#include <hip/hip_runtime.h>
#include <hip/hip_fp16.h>

#define N_NODES 50000
#define N_EDGES 600000
#define D_IN 128
#define D_OUT 256

typedef __attribute__((ext_vector_type(8))) short short8v;
typedef __attribute__((ext_vector_type(4))) float float4v;

#define NB_CONVH 1563   // 256 thr * 16 f32 = 4096 elems/block
#define NB_CONVW 16     // 256 thr * 8 elems
#define NB_ZERO  49     // 12500 int4 / 256

__device__ inline unsigned bfbits(float f) {
    unsigned u = __float_as_uint(f);
    return (u + 0x7FFFu + ((u >> 16) & 1u)) >> 16;   // RNE f32 -> bf16 bits
}
__device__ inline unsigned pack2(float lo, float hi) {
    return bfbits(lo) | (bfbits(hi) << 16);
}

// ---------- Stage 0: pure-streaming prep: h->bf16, W->Wt bf16, zero counts --
__global__ __launch_bounds__(256)
void prep_streams(const float* __restrict__ h, unsigned short* __restrict__ hb,
                  const float* __restrict__ W, unsigned short* __restrict__ wt,
                  int4* __restrict__ counts4) {
    const int bid = blockIdx.x;
    const int t = threadIdx.x;
    if (bid < NB_CONVH) {
        const size_t idx0 = ((size_t)bid * 256 + t) * 16;
        if (idx0 < (size_t)N_NODES * D_IN) {   // multiple of 16 -> full/none
            float4 a = *reinterpret_cast<const float4*>(h + idx0);
            float4 b = *reinterpret_cast<const float4*>(h + idx0 + 4);
            float4 c = *reinterpret_cast<const float4*>(h + idx0 + 8);
            float4 d = *reinterpret_cast<const float4*>(h + idx0 + 12);
            uint4 o1, o2;
            o1.x = pack2(a.x, a.y); o1.y = pack2(a.z, a.w);
            o1.z = pack2(b.x, b.y); o1.w = pack2(b.z, b.w);
            o2.x = pack2(c.x, c.y); o2.y = pack2(c.z, c.w);
            o2.z = pack2(d.x, d.y); o2.w = pack2(d.z, d.w);
            *reinterpret_cast<uint4*>(hb + idx0) = o1;
            *reinterpret_cast<uint4*>(hb + idx0 + 8) = o2;
        }
    } else if (bid < NB_CONVH + NB_CONVW) {
        const int tid = (bid - NB_CONVH) * 256 + t;
        const int n = tid >> 4;
        const int k0 = (tid & 15) * 8;
        uint4 o;
        o.x = pack2(W[(size_t)(k0 + 0) * D_OUT + n], W[(size_t)(k0 + 1) * D_OUT + n]);
        o.y = pack2(W[(size_t)(k0 + 2) * D_OUT + n], W[(size_t)(k0 + 3) * D_OUT + n]);
        o.z = pack2(W[(size_t)(k0 + 4) * D_OUT + n], W[(size_t)(k0 + 5) * D_OUT + n]);
        o.w = pack2(W[(size_t)(k0 + 6) * D_OUT + n], W[(size_t)(k0 + 7) * D_OUT + n]);
        *reinterpret_cast<uint4*>(wt + (size_t)n * D_IN + k0) = o;
    } else {
        const int i = (bid - NB_CONVH - NB_CONVW) * 256 + t;
        if (i < N_NODES / 4) counts4[i] = make_int4(0, 0, 0, 0);
    }
}

// ---------- Stage 1a: histogram, 1 edge/thread (max TLP for atomics) -------
__global__ __launch_bounds__(256)
void hist_dst(const int* __restrict__ edst, int* __restrict__ counts) {
    const int e = blockIdx.x * 256 + threadIdx.x;
    if (e < N_EDGES) atomicAdd(&counts[edst[e]], 1);
}

// ---------- Stage 1b: exclusive scan, 8 elems/thread ----------
__global__ __launch_bounds__(1024)
void scan_counts(const int* __restrict__ counts, int* __restrict__ row_ptr,
                 int* __restrict__ cursor) {
    __shared__ int wave_sums[16];
    __shared__ int wave_offs[16];
    __shared__ int s_total;
    const int t = threadIdx.x;
    const int lane = t & 63;
    const int wv = t >> 6;
    int running = 0;
    for (int base = 0; base < N_NODES; base += 8192) {
        const int i0 = base + t * 8;
        int v[8];
        if (i0 < N_NODES) {
            int4 a = *reinterpret_cast<const int4*>(counts + i0);
            int4 b = *reinterpret_cast<const int4*>(counts + i0 + 4);
            v[0] = a.x; v[1] = a.y; v[2] = a.z; v[3] = a.w;
            v[4] = b.x; v[5] = b.y; v[6] = b.z; v[7] = b.w;
        } else {
            #pragma unroll
            for (int j = 0; j < 8; ++j) v[j] = 0;
        }
        int s[8];
        s[0] = v[0];
        #pragma unroll
        for (int j = 1; j < 8; ++j) s[j] = s[j - 1] + v[j];
        const int tot = s[7];
        int ws = tot;
        #pragma unroll
        for (int d = 1; d < 64; d <<= 1) {
            int u = __shfl_up(ws, d, 64);
            if (lane >= d) ws += u;
        }
        const int texcl = ws - tot;
        if (lane == 63) wave_sums[wv] = ws;
        __syncthreads();
        if (wv == 0 && lane < 16) {
            int w0 = wave_sums[lane];
            int inc = w0;
            #pragma unroll
            for (int d = 1; d < 16; d <<= 1) {
                int u = __shfl_up(inc, d, 64);
                if (lane >= d) inc += u;
            }
            wave_offs[lane] = inc - w0;
            if (lane == 15) s_total = inc;
        }
        __syncthreads();
        if (i0 < N_NODES) {
            const int eb = running + wave_offs[wv] + texcl;
            int4 o1 = make_int4(eb, eb + s[0], eb + s[1], eb + s[2]);
            int4 o2 = make_int4(eb + s[3], eb + s[4], eb + s[5], eb + s[6]);
            *reinterpret_cast<int4*>(row_ptr + i0) = o1;
            *reinterpret_cast<int4*>(row_ptr + i0 + 4) = o2;
            *reinterpret_cast<int4*>(cursor + i0) = o1;
            *reinterpret_cast<int4*>(cursor + i0 + 4) = o2;
        }
        running += s_total;
    }
    if (t == 0) row_ptr[N_NODES] = running;
}

// ---------- Stage 1c: CSR fill, 1 edge/thread, 4B packed entries ----------
// entry = (fp16(weight) << 16) | src   (src < 50000 < 2^16)
__global__ __launch_bounds__(256)
void fill_csr(const int* __restrict__ esrc, const int* __restrict__ edst,
              const float* __restrict__ ew, int* __restrict__ cursor,
              unsigned* __restrict__ srt) {
    const int e = blockIdx.x * 256 + threadIdx.x;
    if (e >= N_EDGES) return;
    const int d = edst[e];
    const unsigned entry =
        ((unsigned)__half_as_ushort(__float2half(ew[e])) << 16) | (unsigned)esrc[e];
    const int p = atomicAdd(&cursor[d], 1);
    srt[p] = entry;
}

// ---------- Stage 2 (fused): 16 waves/block, 1 node/wave gather -> MFMA ----
// Block = 1024 thr = 16 waves = 16 nodes. Wave wv gathers node blk*16+wv into
// LDS row wv (full 50K-wave TLP, unlike R5). After barrier, wave wv computes
// the 16x16 output tile at cols wv*16 for the block's 16 rows.
__global__ __launch_bounds__(1024, 8)
void gather_gemm(const unsigned short* __restrict__ hb,
                 const int* __restrict__ row_ptr,
                 const unsigned* __restrict__ srt,
                 const unsigned short* __restrict__ wt,
                 float* __restrict__ out) {
    __shared__ unsigned short xlds[16 * 136];   // stride 136 shorts: bank-clean
    const int wv = threadIdx.x >> 6;
    const int lane = threadIdx.x & 63;
    const int half = lane >> 5;
    const int sl = lane & 31;
    const int n = blockIdx.x * 16 + wv;         // grid exact: 3125*16 = 50000

    {
        const int beg = row_ptr[n];
        const int end = row_ptr[n + 1];
        float4 acc[4];
        #pragma unroll
        for (int j = 0; j < 4; ++j) acc[j] = make_float4(0.f, 0.f, 0.f, 0.f);
        int e = beg;
        for (; e + 8 <= end; e += 8) {
            #pragma unroll
            for (int j = 0; j < 4; ++j) {
                unsigned p = srt[e + 2 * j + half];
                uint2 hv = *reinterpret_cast<const uint2*>(hb + (size_t)(p & 0xFFFFu) * D_IN + sl * 4);
                float w = __half2float(__ushort_as_half((unsigned short)(p >> 16)));
                acc[j].x = fmaf(w, __uint_as_float(hv.x << 16), acc[j].x);
                acc[j].y = fmaf(w, __uint_as_float(hv.x & 0xFFFF0000u), acc[j].y);
                acc[j].z = fmaf(w, __uint_as_float(hv.y << 16), acc[j].z);
                acc[j].w = fmaf(w, __uint_as_float(hv.y & 0xFFFF0000u), acc[j].w);
            }
        }
        for (; e + 2 <= end; e += 2) {
            unsigned p = srt[e + half];
            uint2 hv = *reinterpret_cast<const uint2*>(hb + (size_t)(p & 0xFFFFu) * D_IN + sl * 4);
            float w = __half2float(__ushort_as_half((unsigned short)(p >> 16)));
            acc[0].x = fmaf(w, __uint_as_float(hv.x << 16), acc[0].x);
            acc[0].y = fmaf(w, __uint_as_float(hv.x & 0xFFFF0000u), acc[0].y);
            acc[0].z = fmaf(w, __uint_as_float(hv.y << 16), acc[0].z);
            acc[0].w = fmaf(w, __uint_as_float(hv.y & 0xFFFF0000u), acc[0].w);
        }
        if (e < end && half == 0) {
            unsigned p = srt[e];
            uint2 hv = *reinterpret_cast<const uint2*>(hb + (size_t)(p & 0xFFFFu) * D_IN + sl * 4);
            float w = __half2float(__ushort_as_half((unsigned short)(p >> 16)));
            acc[1].x = fmaf(w, __uint_as_float(hv.x << 16), acc[1].x);
            acc[1].y = fmaf(w, __uint_as_float(hv.x & 0xFFFF0000u), acc[1].y);
            acc[1].z = fmaf(w, __uint_as_float(hv.y << 16), acc[1].z);
            acc[1].w = fmaf(w, __uint_as_float(hv.y & 0xFFFF0000u), acc[1].w);
        }
        float4 sum;
        sum.x = (acc[0].x + acc[1].x) + (acc[2].x + acc[3].x);
        sum.y = (acc[0].y + acc[1].y) + (acc[2].y + acc[3].y);
        sum.z = (acc[0].z + acc[1].z) + (acc[2].z + acc[3].z);
        sum.w = (acc[0].w + acc[1].w) + (acc[2].w + acc[3].w);
        sum.x += __shfl_xor(sum.x, 32, 64);
        sum.y += __shfl_xor(sum.y, 32, 64);
        sum.z += __shfl_xor(sum.z, 32, 64);
        sum.w += __shfl_xor(sum.w, 32, 64);
        if (half == 0) {
            uint2 o;
            o.x = pack2(sum.x, sum.y);
            o.y = pack2(sum.z, sum.w);
            *reinterpret_cast<uint2*>(&xlds[wv * 136 + sl * 4]) = o;
        }
    }
    __syncthreads();

    // A/B frag: row(col)=lane&15, k=(lane>>4)*8+i. C: col=lane&15, row=g*4+q.
    const int g = lane >> 4;
    const int r = lane & 15;
    short8v a[4];
    const unsigned short* ar = &xlds[r * 136 + g * 8];
    #pragma unroll
    for (int s = 0; s < 4; ++s)
        a[s] = *reinterpret_cast<const short8v*>(ar + 32 * s);

    const int row0 = blockIdx.x * 16;
    const int col0 = wv * 16;
    const unsigned short* brow = wt + (size_t)(col0 + r) * D_IN + g * 8;
    float4v acc = {0.f, 0.f, 0.f, 0.f};
    #pragma unroll
    for (int s = 0; s < 4; ++s) {
        short8v b = *reinterpret_cast<const short8v*>(brow + 32 * s);
        acc = __builtin_amdgcn_mfma_f32_16x16x32_bf16(a[s], b, acc, 0, 0, 0);
    }
    #pragma unroll
    for (int q = 0; q < 4; ++q) {
        out[(size_t)(row0 + g * 4 + q) * D_OUT + col0 + r] = fmaxf(acc[q], 0.f);
    }
}

extern "C" void kernel_launch(void* const* d_in, const int* in_sizes, int n_in,
                              void* d_out, int out_size, void* d_ws, size_t ws_size,
                              hipStream_t stream) {
    const float* h  = (const float*)d_in[0];
    const int* esrc = (const int*)d_in[1];
    const int* edst = (const int*)d_in[2];
    const float* ew = (const float*)d_in[3];
    const float* Wn = (const float*)d_in[4];
    float* out = (float*)d_out;

    // workspace layout (byte offsets, all 16B-aligned)
    char* ws = (char*)d_ws;
    unsigned short* hb  = (unsigned short*)(ws);                // 12,800,000 B
    unsigned short* wt  = (unsigned short*)(ws + 12800000);     //     65,536 B
    int*   counts       = (int*)(ws + 12865536);                //    200,000 B
    int*   row_ptr      = (int*)(ws + 13065536);                //    200,032 B
    int*   cursor       = (int*)(ws + 13265568);                //    200,000 B
    unsigned* srt       = (unsigned*)(ws + 13465568);           //  2,400,000 B
    // total 15,865,568 B

    prep_streams<<<NB_CONVH + NB_CONVW + NB_ZERO, 256, 0, stream>>>(h, hb, Wn, wt, (int4*)counts);
    const int eblocks = (N_EDGES + 255) / 256;
    hist_dst<<<eblocks, 256, 0, stream>>>(edst, counts);
    scan_counts<<<1, 1024, 0, stream>>>(counts, row_ptr, cursor);
    fill_csr<<<eblocks, 256, 0, stream>>>(esrc, edst, ew, cursor, srt);
    gather_gemm<<<N_NODES / 16, 1024, 0, stream>>>(hb, row_ptr, srt, wt, out);
}

// Round 8
// 149.728 us; speedup vs baseline: 7.2279x; 1.0236x over previous
//
#include <hip/hip_runtime.h>
#include <hip/hip_fp16.h>

#define N_NODES 50000
#define N_EDGES 600000
#define D_IN 128
#define D_OUT 256

typedef __attribute__((ext_vector_type(8))) short short8v;
typedef __attribute__((ext_vector_type(4))) float float4v;

#define NB_CONVH 1563   // 256 thr * 16 f32 = 4096 elems/block
#define NB_CONVW 16     // 256 thr * 8 elems
#define NB_ZERO  49     // 12500 int4 / 256

__device__ inline unsigned bfbits(float f) {
    unsigned u = __float_as_uint(f);
    return (u + 0x7FFFu + ((u >> 16) & 1u)) >> 16;   // RNE f32 -> bf16 bits
}
__device__ inline unsigned pack2(float lo, float hi) {
    return bfbits(lo) | (bfbits(hi) << 16);
}

// ---------- Stage 0: pure-streaming prep: h->bf16, W->Wt bf16, zero counts --
__global__ __launch_bounds__(256)
void prep_streams(const float* __restrict__ h, unsigned short* __restrict__ hb,
                  const float* __restrict__ W, unsigned short* __restrict__ wt,
                  int4* __restrict__ counts4) {
    const int bid = blockIdx.x;
    const int t = threadIdx.x;
    if (bid < NB_CONVH) {
        const size_t idx0 = ((size_t)bid * 256 + t) * 16;
        if (idx0 < (size_t)N_NODES * D_IN) {   // multiple of 16 -> full/none
            float4 a = *reinterpret_cast<const float4*>(h + idx0);
            float4 b = *reinterpret_cast<const float4*>(h + idx0 + 4);
            float4 c = *reinterpret_cast<const float4*>(h + idx0 + 8);
            float4 d = *reinterpret_cast<const float4*>(h + idx0 + 12);
            uint4 o1, o2;
            o1.x = pack2(a.x, a.y); o1.y = pack2(a.z, a.w);
            o1.z = pack2(b.x, b.y); o1.w = pack2(b.z, b.w);
            o2.x = pack2(c.x, c.y); o2.y = pack2(c.z, c.w);
            o2.z = pack2(d.x, d.y); o2.w = pack2(d.z, d.w);
            *reinterpret_cast<uint4*>(hb + idx0) = o1;
            *reinterpret_cast<uint4*>(hb + idx0 + 8) = o2;
        }
    } else if (bid < NB_CONVH + NB_CONVW) {
        const int tid = (bid - NB_CONVH) * 256 + t;
        const int n = tid >> 4;
        const int k0 = (tid & 15) * 8;
        uint4 o;
        o.x = pack2(W[(size_t)(k0 + 0) * D_OUT + n], W[(size_t)(k0 + 1) * D_OUT + n]);
        o.y = pack2(W[(size_t)(k0 + 2) * D_OUT + n], W[(size_t)(k0 + 3) * D_OUT + n]);
        o.z = pack2(W[(size_t)(k0 + 4) * D_OUT + n], W[(size_t)(k0 + 5) * D_OUT + n]);
        o.w = pack2(W[(size_t)(k0 + 6) * D_OUT + n], W[(size_t)(k0 + 7) * D_OUT + n]);
        *reinterpret_cast<uint4*>(wt + (size_t)n * D_IN + k0) = o;
    } else {
        const int i = (bid - NB_CONVH - NB_CONVW) * 256 + t;
        if (i < N_NODES / 4) counts4[i] = make_int4(0, 0, 0, 0);
    }
}

// ---------- Stage 1a: histogram, 1 edge/thread (max TLP for atomics) -------
__global__ __launch_bounds__(256)
void hist_dst(const int* __restrict__ edst, int* __restrict__ counts) {
    const int e = blockIdx.x * 256 + threadIdx.x;
    if (e < N_EDGES) atomicAdd(&counts[edst[e]], 1);
}

// ---------- Stage 1b: exclusive scan, 8 elems/thread ----------
__global__ __launch_bounds__(1024)
void scan_counts(const int* __restrict__ counts, int* __restrict__ row_ptr,
                 int* __restrict__ cursor) {
    __shared__ int wave_sums[16];
    __shared__ int wave_offs[16];
    __shared__ int s_total;
    const int t = threadIdx.x;
    const int lane = t & 63;
    const int wv = t >> 6;
    int running = 0;
    for (int base = 0; base < N_NODES; base += 8192) {
        const int i0 = base + t * 8;
        int v[8];
        if (i0 < N_NODES) {
            int4 a = *reinterpret_cast<const int4*>(counts + i0);
            int4 b = *reinterpret_cast<const int4*>(counts + i0 + 4);
            v[0] = a.x; v[1] = a.y; v[2] = a.z; v[3] = a.w;
            v[4] = b.x; v[5] = b.y; v[6] = b.z; v[7] = b.w;
        } else {
            #pragma unroll
            for (int j = 0; j < 8; ++j) v[j] = 0;
        }
        int s[8];
        s[0] = v[0];
        #pragma unroll
        for (int j = 1; j < 8; ++j) s[j] = s[j - 1] + v[j];
        const int tot = s[7];
        int ws = tot;
        #pragma unroll
        for (int d = 1; d < 64; d <<= 1) {
            int u = __shfl_up(ws, d, 64);
            if (lane >= d) ws += u;
        }
        const int texcl = ws - tot;
        if (lane == 63) wave_sums[wv] = ws;
        __syncthreads();
        if (wv == 0 && lane < 16) {
            int w0 = wave_sums[lane];
            int inc = w0;
            #pragma unroll
            for (int d = 1; d < 16; d <<= 1) {
                int u = __shfl_up(inc, d, 64);
                if (lane >= d) inc += u;
            }
            wave_offs[lane] = inc - w0;
            if (lane == 15) s_total = inc;
        }
        __syncthreads();
        if (i0 < N_NODES) {
            const int eb = running + wave_offs[wv] + texcl;
            int4 o1 = make_int4(eb, eb + s[0], eb + s[1], eb + s[2]);
            int4 o2 = make_int4(eb + s[3], eb + s[4], eb + s[5], eb + s[6]);
            *reinterpret_cast<int4*>(row_ptr + i0) = o1;
            *reinterpret_cast<int4*>(row_ptr + i0 + 4) = o2;
            *reinterpret_cast<int4*>(cursor + i0) = o1;
            *reinterpret_cast<int4*>(cursor + i0 + 4) = o2;
        }
        running += s_total;
    }
    if (t == 0) row_ptr[N_NODES] = running;
}

// ---------- Stage 1c: CSR fill, 1 edge/thread, 4B packed entries ----------
// entry = (fp16(weight) << 16) | src   (src < 50000 < 2^16)
__global__ __launch_bounds__(256)
void fill_csr(const int* __restrict__ esrc, const int* __restrict__ edst,
              const float* __restrict__ ew, int* __restrict__ cursor,
              unsigned* __restrict__ srt) {
    const int e = blockIdx.x * 256 + threadIdx.x;
    if (e >= N_EDGES) return;
    const int d = edst[e];
    const unsigned entry =
        ((unsigned)__half_as_ushort(__float2half(ew[e])) << 16) | (unsigned)esrc[e];
    const int p = atomicAdd(&cursor[d], 1);
    srt[p] = entry;
}

// ---------- Stage 1d: gather-reduce, 1 node/wave, shuffle-distributed CSR --
// One coalesced wave-load grabs up to 64 packed entries; __shfl distributes
// them, so h-row loads have no upstream memory dependence and pipeline deep.
__global__ __launch_bounds__(256)
void gather_nodes(const unsigned short* __restrict__ hb,
                  const int* __restrict__ row_ptr,
                  const unsigned* __restrict__ srt,
                  unsigned short* __restrict__ xb) {
    const int wv = threadIdx.x >> 6;
    const int lane = threadIdx.x & 63;
    const int n = blockIdx.x * 4 + wv;
    if (n >= N_NODES) return;
    const int beg = row_ptr[n];
    const int end = row_ptr[n + 1];
    const int half = lane >> 5;       // which edge of a processed pair
    const int sl = lane & 31;         // 4 dims per lane
    float4 acc[4];
    #pragma unroll
    for (int i = 0; i < 4; ++i) acc[i] = make_float4(0.f, 0.f, 0.f, 0.f);

    for (int base = beg; base < end; base += 64) {
        const int cnt = min(64, end - base);
        unsigned ent = (base + lane < end) ? srt[base + lane] : 0u;
        int j = 0;
        for (; j + 8 <= cnt; j += 8) {
            #pragma unroll
            for (int i = 0; i < 4; ++i) {
                const unsigned p = __shfl(ent, j + 2 * i + half, 64);
                uint2 hv = *reinterpret_cast<const uint2*>(
                    hb + (size_t)(p & 0xFFFFu) * D_IN + sl * 4);
                const float w = __half2float(__ushort_as_half((unsigned short)(p >> 16)));
                acc[i].x = fmaf(w, __uint_as_float(hv.x << 16), acc[i].x);
                acc[i].y = fmaf(w, __uint_as_float(hv.x & 0xFFFF0000u), acc[i].y);
                acc[i].z = fmaf(w, __uint_as_float(hv.y << 16), acc[i].z);
                acc[i].w = fmaf(w, __uint_as_float(hv.y & 0xFFFF0000u), acc[i].w);
            }
        }
        for (; j + 2 <= cnt; j += 2) {
            const unsigned p = __shfl(ent, j + half, 64);
            uint2 hv = *reinterpret_cast<const uint2*>(
                hb + (size_t)(p & 0xFFFFu) * D_IN + sl * 4);
            const float w = __half2float(__ushort_as_half((unsigned short)(p >> 16)));
            acc[0].x = fmaf(w, __uint_as_float(hv.x << 16), acc[0].x);
            acc[0].y = fmaf(w, __uint_as_float(hv.x & 0xFFFF0000u), acc[0].y);
            acc[0].z = fmaf(w, __uint_as_float(hv.y << 16), acc[0].z);
            acc[0].w = fmaf(w, __uint_as_float(hv.y & 0xFFFF0000u), acc[0].w);
        }
        if (j < cnt) {
            const unsigned p = __shfl(ent, j, 64);
            if (half == 0) {
                uint2 hv = *reinterpret_cast<const uint2*>(
                    hb + (size_t)(p & 0xFFFFu) * D_IN + sl * 4);
                const float w = __half2float(__ushort_as_half((unsigned short)(p >> 16)));
                acc[1].x = fmaf(w, __uint_as_float(hv.x << 16), acc[1].x);
                acc[1].y = fmaf(w, __uint_as_float(hv.x & 0xFFFF0000u), acc[1].y);
                acc[1].z = fmaf(w, __uint_as_float(hv.y << 16), acc[1].z);
                acc[1].w = fmaf(w, __uint_as_float(hv.y & 0xFFFF0000u), acc[1].w);
            }
        }
    }
    float4 sum;
    sum.x = (acc[0].x + acc[1].x) + (acc[2].x + acc[3].x);
    sum.y = (acc[0].y + acc[1].y) + (acc[2].y + acc[3].y);
    sum.z = (acc[0].z + acc[1].z) + (acc[2].z + acc[3].z);
    sum.w = (acc[0].w + acc[1].w) + (acc[2].w + acc[3].w);
    sum.x += __shfl_xor(sum.x, 32, 64);
    sum.y += __shfl_xor(sum.y, 32, 64);
    sum.z += __shfl_xor(sum.z, 32, 64);
    sum.w += __shfl_xor(sum.w, 32, 64);
    if (half == 0) {
        uint2 o;
        o.x = pack2(sum.x, sum.y);
        o.y = pack2(sum.z, sum.w);
        *reinterpret_cast<uint2*>(xb + (size_t)n * D_IN + sl * 4) = o;
    }
}

// ---------- Stage 2: out = relu(x_bf16 @ Wt^T) via MFMA ----------
__global__ __launch_bounds__(256)
void gemm_mfma(const unsigned short* __restrict__ xb,
               const unsigned short* __restrict__ wt,
               float* __restrict__ out) {
    const int wv = threadIdx.x >> 6;
    const int lane = threadIdx.x & 63;
    const int row0 = blockIdx.x * 64 + wv * 16;
    if (row0 >= N_NODES) return;
    const int g = lane >> 4;
    const int r = lane & 15;

    short8v a[4];
    const unsigned short* arow = xb + (size_t)(row0 + r) * D_IN + g * 8;
    #pragma unroll
    for (int s = 0; s < 4; ++s)
        a[s] = *reinterpret_cast<const short8v*>(arow + 32 * s);

    #pragma unroll
    for (int t = 0; t < 16; ++t) {
        const unsigned short* brow = wt + (size_t)(t * 16 + r) * D_IN + g * 8;
        float4v acc = {0.f, 0.f, 0.f, 0.f};
        #pragma unroll
        for (int s = 0; s < 4; ++s) {
            short8v b = *reinterpret_cast<const short8v*>(brow + 32 * s);
            acc = __builtin_amdgcn_mfma_f32_16x16x32_bf16(a[s], b, acc, 0, 0, 0);
        }
        #pragma unroll
        for (int q = 0; q < 4; ++q) {
            out[(size_t)(row0 + g * 4 + q) * D_OUT + t * 16 + r] = fmaxf(acc[q], 0.f);
        }
    }
}

extern "C" void kernel_launch(void* const* d_in, const int* in_sizes, int n_in,
                              void* d_out, int out_size, void* d_ws, size_t ws_size,
                              hipStream_t stream) {
    const float* h  = (const float*)d_in[0];
    const int* esrc = (const int*)d_in[1];
    const int* edst = (const int*)d_in[2];
    const float* ew = (const float*)d_in[3];
    const float* Wn = (const float*)d_in[4];
    float* out = (float*)d_out;

    // workspace layout (byte offsets, all 16B-aligned)
    char* ws = (char*)d_ws;
    unsigned short* hb  = (unsigned short*)(ws);                // 12,800,000 B
    unsigned short* xb  = (unsigned short*)(ws + 12800000);     // 12,800,000 B
    unsigned short* wt  = (unsigned short*)(ws + 25600000);     //     65,536 B
    int*   counts       = (int*)(ws + 25665536);                //    200,000 B
    int*   row_ptr      = (int*)(ws + 25865536);                //    200,032 B
    int*   cursor       = (int*)(ws + 26065568);                //    200,000 B
    unsigned* srt       = (unsigned*)(ws + 26265568);           //  2,400,000 B
    // total 28,665,568 B

    prep_streams<<<NB_CONVH + NB_CONVW + NB_ZERO, 256, 0, stream>>>(h, hb, Wn, wt, (int4*)counts);
    const int eblocks = (N_EDGES + 255) / 256;
    hist_dst<<<eblocks, 256, 0, stream>>>(edst, counts);
    scan_counts<<<1, 1024, 0, stream>>>(counts, row_ptr, cursor);
    fill_csr<<<eblocks, 256, 0, stream>>>(esrc, edst, ew, cursor, srt);
    gather_nodes<<<(N_NODES + 3) / 4, 256, 0, stream>>>(hb, row_ptr, srt, xb);
    gemm_mfma<<<(N_NODES + 63) / 64, 256, 0, stream>>>(xb, wt, out);
}